// Round 5
// baseline (613.707 us; speedup 1.0000x reference)
//
#include <hip/hip_runtime.h>
#include <math.h>

#define BATCH 32768
#define NCH   2048
#define NCH4  512            // f32x4 per row
#define NBLK  1024
#define NTHR  256
#define VPT   64             // f32x4 held per thread: 32 rows * 512 / 256 thr
#define NSLICE 128           // phase-2 slices (each sums 8 partial rows)

typedef float f32x4 __attribute__((ext_vector_type(4)));

// ---------------------------------------------------------------------------
// Device-wide barrier. cnt/flag zeroed by hipMemsetAsync before each launch.
// All 1024 blocks are co-resident (see launch_bounds/capacity analysis), so
// spinning is deadlock-free. Device-scope atomics -> valid across XCDs.
// ---------------------------------------------------------------------------
__device__ __forceinline__ void grid_barrier(unsigned* cnt, unsigned* flag,
                                             unsigned nblk) {
    __threadfence();                      // release this block's prior writes
    __syncthreads();
    if (threadIdx.x == 0) {
        unsigned prev = __hip_atomic_fetch_add(cnt, 1u, __ATOMIC_ACQ_REL,
                                               __HIP_MEMORY_SCOPE_AGENT);
        if (prev == nblk - 1u) {
            __hip_atomic_store(flag, 1u, __ATOMIC_RELEASE,
                               __HIP_MEMORY_SCOPE_AGENT);
        } else {
            while (__hip_atomic_load(flag, __ATOMIC_ACQUIRE,
                                     __HIP_MEMORY_SCOPE_AGENT) == 0u)
                __builtin_amdgcn_s_sleep(2);
        }
    }
    __syncthreads();
}

__device__ __forceinline__ float gate1(float s, float fr, float pa, float spv,
                                       float dec, float wsc, float rw) {
    float phi = pa * dec + s * (1.0f / (float)BATCH);
    float t  = __cosf(phi - fr) * 0.5f + 0.5f;
    float t2 = t * t, t4 = t2 * t2, t8 = t4 * t4;
    float res = t8 * t2;                                  // t^10
    float sp = __sinf((float)M_PI * spv);
    float wave = sp * sp * __cosf(phi) * wsc;
    return res + rw * wave;
}

// ---------------------------------------------------------------------------
// Persistent fused kernel: x lives in VGPRs across the whole pipeline.
//  P1: load 64 f32x4/thread (block b owns rows [b*32,b*32+32)), accumulate
//      per-thread column partials (thread t owns ch 4t..4t+3 & 1024+4t..+3),
//      NT-store block partial row (2048 floats).
//  B1: grid barrier.
//  P2: gid=(b,t) -> (slice s=gid>>11, channel c=gid&2047): sum 8 partial rows,
//      one device atomicAdd into gsum[c]  (128-deep per channel).
//  B2: grid barrier.
//  P3: per-thread compute g for its 8 channels (fast sin/cos, redundant),
//      gate the 64 register-resident f32x4, NT-store out.
// HBM: read x once (256MiB) + partials 8MiB x2 + write out 256MiB.
// ---------------------------------------------------------------------------
__global__ __launch_bounds__(NTHR, 4) void fused_kernel(
        const float* __restrict__ x,
        const float* __restrict__ freqs,
        const float* __restrict__ pdec,
        const float* __restrict__ wscl,
        const float* __restrict__ rwgt,
        const float* __restrict__ pacc,
        const float* __restrict__ spe,
        float* __restrict__ out,
        float* __restrict__ ws) {
    unsigned* cnt1 = (unsigned*)ws;            // byte 0
    unsigned* flag1 = (unsigned*)ws + 32;      // byte 128
    unsigned* cnt2 = (unsigned*)ws + 64;       // byte 256
    unsigned* flag2 = (unsigned*)ws + 96;      // byte 384
    float* gsum    = ws + 1024;                // byte 4096, 2048 floats
    float* partial = ws + 4096;                // byte 16384, NBLK*NCH floats

    const int t = threadIdx.x;
    const int b = blockIdx.x;

    const f32x4* __restrict__ x4 = (const f32x4*)x;
    const size_t base = (size_t)b * (32 * NCH4) + t;      // + j*NTHR

    // ---- Phase 1: load x into registers, accumulate column partials ----
    f32x4 v[VPT];
    #pragma unroll
    for (int j = 0; j < VPT; ++j)
        v[j] = x4[base + (size_t)j * NTHR];

    f32x4 a0 = {0.f, 0.f, 0.f, 0.f};   // channels 4t..4t+3   (even j)
    f32x4 a1 = {0.f, 0.f, 0.f, 0.f};   // channels 1024+4t..  (odd j)
    #pragma unroll
    for (int j = 0; j < VPT; j += 2) {
        a0 += v[j];
        a1 += v[j + 1];
    }

    f32x4* p4 = (f32x4*)partial + (size_t)b * NCH4;
    __builtin_nontemporal_store(a0, &p4[t]);
    __builtin_nontemporal_store(a1, &p4[256 + t]);

    grid_barrier(cnt1, flag1, NBLK);

    // ---- Phase 2: reduce partials -> gsum via device atomics ----
    {
        const int gid = b * NTHR + t;          // 0..262143
        const int c = gid & (NCH - 1);
        const int s = gid >> 11;               // 0..127
        float acc = 0.f;
        #pragma unroll
        for (int k = 0; k < 8; ++k)
            acc += partial[(size_t)(s * 8 + k) * NCH + c];
        atomicAdd(&gsum[c], acc);
    }

    grid_barrier(cnt2, flag2, NBLK);

    // ---- Phase 3: compute g for this thread's 8 channels, gate, store ----
    const f32x4* gs4 = (const f32x4*)gsum;
    const f32x4* fr4 = (const f32x4*)freqs;
    const f32x4* pa4 = (const f32x4*)pacc;
    const f32x4* sp4 = (const f32x4*)spe;
    const float dec = pdec[0], wsc = wscl[0], rw = rwgt[0];

    f32x4 s0 = gs4[t],        s1 = gs4[256 + t];
    f32x4 f0 = fr4[t],        f1 = fr4[256 + t];
    f32x4 q0 = pa4[t],        q1 = pa4[256 + t];
    f32x4 e0 = sp4[t],        e1 = sp4[256 + t];

    f32x4 g0, g1;
    g0.x = gate1(s0.x, f0.x, q0.x, e0.x, dec, wsc, rw);
    g0.y = gate1(s0.y, f0.y, q0.y, e0.y, dec, wsc, rw);
    g0.z = gate1(s0.z, f0.z, q0.z, e0.z, dec, wsc, rw);
    g0.w = gate1(s0.w, f0.w, q0.w, e0.w, dec, wsc, rw);
    g1.x = gate1(s1.x, f1.x, q1.x, e1.x, dec, wsc, rw);
    g1.y = gate1(s1.y, f1.y, q1.y, e1.y, dec, wsc, rw);
    g1.z = gate1(s1.z, f1.z, q1.z, e1.z, dec, wsc, rw);
    g1.w = gate1(s1.w, f1.w, q1.w, e1.w, dec, wsc, rw);

    f32x4* __restrict__ o4 = (f32x4*)out;

#define GATEF(zv, ov)                                                 \
    do {                                                              \
        (ov).x = (zv).x * (1.0f - __expf(-fabsf((zv).x)));            \
        (ov).y = (zv).y * (1.0f - __expf(-fabsf((zv).y)));            \
        (ov).z = (zv).z * (1.0f - __expf(-fabsf((zv).z)));            \
        (ov).w = (zv).w * (1.0f - __expf(-fabsf((zv).w)));            \
    } while (0)

    #pragma unroll
    for (int j = 0; j < VPT; j += 2) {
        f32x4 z0 = v[j] * g0;
        f32x4 z1 = v[j + 1] * g1;
        f32x4 o0, o1;
        GATEF(z0, o0);
        GATEF(z1, o1);
        __builtin_nontemporal_store(o0, &o4[base + (size_t)j * NTHR]);
        __builtin_nontemporal_store(o1, &o4[base + (size_t)(j + 1) * NTHR]);
    }
#undef GATEF
}

extern "C" void kernel_launch(void* const* d_in, const int* in_sizes, int n_in,
                              void* d_out, int out_size, void* d_ws, size_t ws_size,
                              hipStream_t stream) {
    const float* x     = (const float*)d_in[0];
    const float* freqs = (const float*)d_in[1];
    const float* pdec  = (const float*)d_in[2];
    const float* wscl  = (const float*)d_in[3];
    const float* rwgt  = (const float*)d_in[4];
    const float* pacc  = (const float*)d_in[5];
    const float* spe   = (const float*)d_in[6];
    float* out = (float*)d_out;
    float* ws  = (float*)d_ws;

    // Zero barrier control words + gsum every call (ws is poisoned once
    // before timing and never restored between replays).
    hipMemsetAsync(ws, 0, 12 * 1024, stream);

    fused_kernel<<<NBLK, NTHR, 0, stream>>>(x, freqs, pdec, wscl, rwgt,
                                            pacc, spe, out, ws);
}

// Round 6
// 149.567 us; speedup vs baseline: 4.1032x; 4.1032x over previous
//
#include <hip/hip_runtime.h>
#include <math.h>

#define BATCH   32768
#define NCH     2048
#define NCH4    512                    // f32x4 per row
#define CS_BLOCKS 1024
#define ROWS_PER_BLOCK 32
#define SLICES 16
#define PIN_ROWS 24576                 // 192 MiB pinned in L3; rest streamed NT
#define NT_BLOCKS 256                  // (32768-24576)/32 blocks handle NT slice

typedef float f32x4 __attribute__((ext_vector_type(4)));

__device__ __forceinline__ f32x4 ldx(const f32x4* __restrict__ p, bool nt) {
    return nt ? __builtin_nontemporal_load(p) : *p;
}

// ---------------------------------------------------------------------------
// Pass 1: per-block partial column sums. Blocks 0..255 (run first) handle the
// STREAMED rows [24576, 32768) with NT loads (no L3 allocate); blocks
// 256..1023 handle the PINNED rows [0, 24576) with regular loads, installing
// 192 MiB of x into the Infinity Cache. partial[b] = d_out scratch.
// ---------------------------------------------------------------------------
__global__ __launch_bounds__(256) void colsum_kernel(const float* __restrict__ x,
                                                     float* __restrict__ partial) {
    const int t = threadIdx.x;
    const int b = blockIdx.x;
    const bool nt = (b < NT_BLOCKS);
    const int row0 = nt ? (PIN_ROWS + ROWS_PER_BLOCK * b)
                        : (ROWS_PER_BLOCK * (b - NT_BLOCKS));

    const f32x4* __restrict__ x4 = (const f32x4*)x;
    size_t base = (size_t)row0 * NCH4 + t;

    f32x4 a0 = {0.f, 0.f, 0.f, 0.f};
    f32x4 a1 = {0.f, 0.f, 0.f, 0.f};

    if (nt) {
        #pragma unroll 4
        for (int r = 0; r < ROWS_PER_BLOCK; ++r) {
            a0 += __builtin_nontemporal_load(&x4[base]);
            a1 += __builtin_nontemporal_load(&x4[base + 256]);
            base += NCH4;
        }
    } else {
        #pragma unroll 4
        for (int r = 0; r < ROWS_PER_BLOCK; ++r) {
            a0 += x4[base];
            a1 += x4[base + 256];
            base += NCH4;
        }
    }

    f32x4* p4 = (f32x4*)partial + (size_t)b * NCH4;
    __builtin_nontemporal_store(a0, &p4[t]);
    __builtin_nontemporal_store(a1, &p4[256 + t]);
}

// ---------------------------------------------------------------------------
// Pass 2a: reduce 1024 partial rows -> 16 sub-partials per channel (NT loads,
// partials are dead after this).
// ---------------------------------------------------------------------------
__global__ __launch_bounds__(256) void gcalcA_kernel(const float* __restrict__ partial,
                                                     float* __restrict__ sub) {
    const int gid = blockIdx.x * 256 + threadIdx.x;     // 0..32767
    const int c = gid & (NCH - 1);
    const int s = gid >> 11;                            // 0..15
    const int p0 = s * (CS_BLOCKS / SLICES);

    float acc = 0.f;
    #pragma unroll 8
    for (int p = 0; p < CS_BLOCKS / SLICES; ++p)
        acc += __builtin_nontemporal_load(&partial[(size_t)(p0 + p) * NCH + c]);
    sub[s * NCH + c] = acc;
}

// ---------------------------------------------------------------------------
// Pass 2b: final reduce + per-channel gate g[c].
// ---------------------------------------------------------------------------
__global__ __launch_bounds__(256) void gcalcB_kernel(const float* __restrict__ sub,
                                                     const float* __restrict__ freqs,
                                                     const float* __restrict__ p_decay,
                                                     const float* __restrict__ w_scale,
                                                     const float* __restrict__ r_weight,
                                                     const float* __restrict__ p_acc,
                                                     const float* __restrict__ spe,
                                                     float* __restrict__ g) {
    const int c = blockIdx.x * 256 + threadIdx.x;       // 0..2047

    float s = 0.f;
    #pragma unroll
    for (int k = 0; k < SLICES; ++k)
        s += sub[k * NCH + c];

    const float phi = p_acc[c] * p_decay[0] + s * (1.0f / (float)BATCH);

    float t = cosf(phi - freqs[c]) * 0.5f + 0.5f;
    float t2 = t * t;
    float t4 = t2 * t2;
    float t8 = t4 * t4;
    float resonance = t8 * t2;                          // t^10

    float sp = sinf((float)M_PI * spe[c]);
    float wave = sp * sp * cosf(phi) * w_scale[0];

    g[c] = resonance + r_weight[0] * wave;
}

// ---------------------------------------------------------------------------
// Pass 3: out = z * (1 - exp(-|z|)),  z = x * g[c].
// Windows j=0..23 cover pinned rows (regular loads -> L3 hits);
// j=24..31 cover streamed rows (NT loads). NT stores for out throughout.
// 4-deep manual prefetch pipeline, forward order.
// ---------------------------------------------------------------------------
__global__ __launch_bounds__(256) void gate_kernel(const float* __restrict__ x,
                                                   const float* __restrict__ g,
                                                   float* __restrict__ out) {
    const f32x4* __restrict__ x4 = (const f32x4*)x;
    const f32x4* __restrict__ g4 = (const f32x4*)g;
    f32x4* __restrict__ o4 = (f32x4*)out;

    const int tid = blockIdx.x * 256 + threadIdx.x;     // 0..524287
    const int stride = 2048 * 256;                      // 524288
    // window j covers rows [j*1024, j*1024+1024); 24576/1024 = 24 boundary

    const f32x4 gv = g4[tid & (NCH4 - 1)];

#define GATEF(v, o)                                                   \
    do {                                                              \
        f32x4 z = (v) * gv;                                           \
        (o).x = z.x * (1.0f - __expf(-fabsf(z.x)));                   \
        (o).y = z.y * (1.0f - __expf(-fabsf(z.y)));                   \
        (o).z = z.z * (1.0f - __expf(-fabsf(z.z)));                   \
        (o).w = z.w * (1.0f - __expf(-fabsf(z.w)));                   \
    } while (0)

    f32x4 v0 = ldx(&x4[tid + 0 * stride], false);
    f32x4 v1 = ldx(&x4[tid + 1 * stride], false);
    f32x4 v2 = ldx(&x4[tid + 2 * stride], false);
    f32x4 v3 = ldx(&x4[tid + 3 * stride], false);

    #pragma unroll
    for (int j = 0; j < 28; j += 4) {
        f32x4 n0 = ldx(&x4[tid + (j + 4) * stride], (j + 4) >= 24);
        f32x4 n1 = ldx(&x4[tid + (j + 5) * stride], (j + 5) >= 24);
        f32x4 n2 = ldx(&x4[tid + (j + 6) * stride], (j + 6) >= 24);
        f32x4 n3 = ldx(&x4[tid + (j + 7) * stride], (j + 7) >= 24);

        f32x4 o0, o1, o2, o3;
        GATEF(v0, o0); GATEF(v1, o1); GATEF(v2, o2); GATEF(v3, o3);
        __builtin_nontemporal_store(o0, &o4[tid + (j + 0) * stride]);
        __builtin_nontemporal_store(o1, &o4[tid + (j + 1) * stride]);
        __builtin_nontemporal_store(o2, &o4[tid + (j + 2) * stride]);
        __builtin_nontemporal_store(o3, &o4[tid + (j + 3) * stride]);

        v0 = n0; v1 = n1; v2 = n2; v3 = n3;
    }

    f32x4 o0, o1, o2, o3;
    GATEF(v0, o0); GATEF(v1, o1); GATEF(v2, o2); GATEF(v3, o3);
    __builtin_nontemporal_store(o0, &o4[tid + 28 * stride]);
    __builtin_nontemporal_store(o1, &o4[tid + 29 * stride]);
    __builtin_nontemporal_store(o2, &o4[tid + 30 * stride]);
    __builtin_nontemporal_store(o3, &o4[tid + 31 * stride]);
#undef GATEF
}

extern "C" void kernel_launch(void* const* d_in, const int* in_sizes, int n_in,
                              void* d_out, int out_size, void* d_ws, size_t ws_size,
                              hipStream_t stream) {
    const float* x     = (const float*)d_in[0];
    const float* freqs = (const float*)d_in[1];
    const float* pdec  = (const float*)d_in[2];
    const float* wscl  = (const float*)d_in[3];
    const float* rwgt  = (const float*)d_in[4];
    const float* pacc  = (const float*)d_in[5];
    const float* spe   = (const float*)d_in[6];
    float* out = (float*)d_out;

    float* partial = out;               // 1024*2048 floats = 8 MiB scratch in
                                        // d_out; gate fully overwrites later
    float* sub = (float*)d_ws;          // 16*2048 floats
    float* g   = sub + SLICES * NCH;    // 2048 floats

    colsum_kernel<<<CS_BLOCKS, 256, 0, stream>>>(x, partial);

    gcalcA_kernel<<<128, 256, 0, stream>>>(partial, sub);

    gcalcB_kernel<<<NCH / 256, 256, 0, stream>>>(sub, freqs, pdec, wscl, rwgt,
                                                 pacc, spe, g);

    gate_kernel<<<2048, 256, 0, stream>>>(x, g, out);
}